// Round 1
// baseline (1410.457 us; speedup 1.0000x reference)
//
#include <hip/hip_runtime.h>

#define SEQ 1024
#define BATCH 512
#define NTAGS 64

// One wave (64 lanes) per batch chain. Lane j owns alpha[j] and column j of
// expT (exp of transitions) in registers. Per active step:
//   m   = wavemax(alpha)                       (6 shfl_xor + max)
//   ea  = exp(alpha - m)                       (1 exp)
//   s_j = sum_i ea[i] * expT[i][j]             (LDS broadcast + 64 FMA)
//   alpha_j = em[t,b,j] + m + log(s_j)         (1 log)
// Numerator fused via wave-uniform scalar loads + one shfl per step.
// mask is a prefix mask (t < length), wave-uniform -> break at first 0.
__launch_bounds__(64)
__global__ void crf_kernel(const float* __restrict__ em,
                           const int* __restrict__ tags,
                           const int* __restrict__ mask,
                           const float* __restrict__ startT,
                           const float* __restrict__ endT,
                           const float* __restrict__ trans,
                           float* __restrict__ out)
{
    const int b = blockIdx.x;
    const int j = threadIdx.x;  // 0..63 == tag index

    __shared__ float ea_sh[NTAGS];

    // Preload expT column j (constant across the whole scan): 64 VGPRs.
    float col[NTAGS];
#pragma unroll
    for (int i = 0; i < NTAGS; ++i)
        col[i] = __expf(trans[i * NTAGS + j]);

    // t = 0
    float em0   = em[(size_t)b * NTAGS + j];
    float alpha = startT[j] + em0;
    int   prev  = tags[b];                       // wave-uniform
    float num   = startT[prev] + __shfl(em0, prev);

    for (int t = 1; t < SEQ; ++t) {
        // prefix mask, wave-uniform: first zero ends the chain
        if (mask[t * BATCH + b] == 0) break;

        float emt = em[((size_t)t * BATCH + b) * NTAGS + j];

        // ---- numerator (wave-uniform scalar work) ----
        int cur = tags[t * BATCH + b];
        num += trans[prev * NTAGS + cur] + __shfl(emt, cur);
        prev = cur;

        // ---- normalizer step ----
        float m = alpha;
#pragma unroll
        for (int off = 32; off > 0; off >>= 1)
            m = fmaxf(m, __shfl_xor(m, off));

        float ea = __expf(alpha - m);

        __syncthreads();
        ea_sh[j] = ea;
        __syncthreads();

        float s0 = 0.f, s1 = 0.f, s2 = 0.f, s3 = 0.f;
        const float4* eav = (const float4*)ea_sh;
#pragma unroll
        for (int i4 = 0; i4 < NTAGS / 4; ++i4) {
            float4 q = eav[i4];                  // same addr all lanes: broadcast
            s0 += q.x * col[4 * i4 + 0];
            s1 += q.y * col[4 * i4 + 1];
            s2 += q.z * col[4 * i4 + 2];
            s3 += q.w * col[4 * i4 + 3];
        }
        float s = (s0 + s1) + (s2 + s3);

        alpha = emt + m + __logf(s);
    }

    num += endT[prev];                           // prev == tag at length-1

    // final logsumexp(alpha + end)
    float v  = alpha + endT[j];
    float m2 = v;
#pragma unroll
    for (int off = 32; off > 0; off >>= 1)
        m2 = fmaxf(m2, __shfl_xor(m2, off));
    float e2 = __expf(v - m2);
#pragma unroll
    for (int off = 32; off > 0; off >>= 1)
        e2 += __shfl_xor(e2, off);
    float denom = m2 + __logf(e2);

    if (j == 0)
        atomicAdd(out, num - denom);
}

extern "C" void kernel_launch(void* const* d_in, const int* in_sizes, int n_in,
                              void* d_out, int out_size, void* d_ws, size_t ws_size,
                              hipStream_t stream)
{
    const float* em     = (const float*)d_in[0];
    const int*   tags   = (const int*)d_in[1];
    const int*   mask   = (const int*)d_in[2];
    const float* startT = (const float*)d_in[3];
    const float* endT   = (const float*)d_in[4];
    const float* trans  = (const float*)d_in[5];
    float*       out    = (float*)d_out;

    hipMemsetAsync(out, 0, sizeof(float) * out_size, stream);
    crf_kernel<<<BATCH, 64, 0, stream>>>(em, tags, mask, startT, endT, trans, out);
}

// Round 2
// 436.307 us; speedup vs baseline: 3.2327x; 3.2327x over previous
//
#include <hip/hip_runtime.h>

#define SEQ 1024
#define BATCH 512
#define NTAGS 64

typedef float v2f __attribute__((ext_vector_type(2)));

// Compiler-only memory fence (no instruction): orders LDS ops for
// wave-synchronous (single-wave lockstep) programming without s_barrier's
// vmcnt(0) drain.
#define WAVE_FENCE() asm volatile("" ::: "memory")

// One wave per chain, linear-space forward algorithm:
//   beta'_j = (sum_i beta_i * expT[i][j]) * exp(em[t,j])
// score_j = M + log(beta_j); renorm (div by 2-step-stale beta_0, folded into
// the exp(em) factor) every 4 steps keeps beta in fp32 range.
// Numerator fused: trans from LDS + one shfl per step, all off critical path.
__global__ __launch_bounds__(64)
void crf_kernel(const float* __restrict__ em,
                const int* __restrict__ tags,
                const int* __restrict__ mask,
                const float* __restrict__ startT,
                const float* __restrict__ endT,
                const float* __restrict__ trans,
                float* __restrict__ out)
{
    const int b = blockIdx.x;
    const int j = threadIdx.x;  // tag index 0..63

    __shared__ float trans_sh[NTAGS * NTAGS];
    __shared__ __align__(16) float beta_sh[NTAGS];

    // expT column j in registers (packed pairs for v_pk_fma_f32), raw trans
    // into LDS for the numerator lookups.
    v2f col2[NTAGS / 2];
#pragma unroll
    for (int i = 0; i < NTAGS; i += 2) {
        float t0 = trans[(i + 0) * NTAGS + j];
        float t1 = trans[(i + 1) * NTAGS + j];
        trans_sh[(i + 0) * NTAGS + j] = t0;
        trans_sh[(i + 1) * NTAGS + j] = t1;
        v2f c; c.x = __expf(t0); c.y = __expf(t1);
        col2[i / 2] = c;
    }

    const float eend = __expf(endT[j]);

    // length of this chain = sum of its (prefix) mask column
    int lsum = 0;
#pragma unroll
    for (int k = 0; k < SEQ / 64; ++k)
        lsum += mask[(k * 64 + j) * BATCH + b];
#pragma unroll
    for (int off = 32; off > 0; off >>= 1)
        lsum += __shfl_xor(lsum, off);
    const int L = lsum;  // in [1, SEQ]

    // ---- t = 0 ----
    float em0   = em[(size_t)b * NTAGS + j];
    float a0j   = startT[j] + em0;
    float M     = __shfl(a0j, 0);
    float beta  = __expf(a0j - M);

    int   prev = tags[b];
    float num  = startT[prev] + __shfl(em0, prev);

    WAVE_FENCE();  // trans_sh fully written (single wave, in-order DS)

    // the 64x64 broadcast dot: s_j = sum_i beta_i * expT[i][j]
#define DOT_BODY(SVAR)                                                    \
    {                                                                     \
        WAVE_FENCE();                                                     \
        beta_sh[j] = beta;                                                \
        WAVE_FENCE();                                                     \
        const float4* bv = (const float4*)beta_sh;                        \
        v2f a0 = {0.f, 0.f}, a1 = {0.f, 0.f}, a2 = {0.f, 0.f}, a3 = {0.f, 0.f}; \
        _Pragma("unroll")                                                 \
        for (int i4 = 0; i4 < 16; i4 += 2) {                              \
            float4 q0 = bv[i4], q1 = bv[i4 + 1];                          \
            v2f q0l; q0l.x = q0.x; q0l.y = q0.y;                          \
            v2f q0h; q0h.x = q0.z; q0h.y = q0.w;                          \
            v2f q1l; q1l.x = q1.x; q1l.y = q1.y;                          \
            v2f q1h; q1h.x = q1.z; q1h.y = q1.w;                          \
            a0 += q0l * col2[2 * i4 + 0];                                 \
            a1 += q0h * col2[2 * i4 + 1];                                 \
            a2 += q1l * col2[2 * i4 + 2];                                 \
            a3 += q1h * col2[2 * i4 + 3];                                 \
        }                                                                 \
        v2f at = (a0 + a1) + (a2 + a3);                                   \
        SVAR = at.x + at.y;                                               \
    }

    int t = 1;

    // prime distance-4 prefetch
    float em_c[4]; int tg_c[4];
#pragma unroll
    for (int u = 0; u < 4; ++u) {
        int tt = t + u; int ttc = tt < SEQ ? tt : SEQ - 1;
        em_c[u] = em[((size_t)ttc * BATCH + b) * NTAGS + j];
        tg_c[u] = tags[ttc * BATCH + b];
    }

    while (t + 3 <= L - 1) {
        // prefetch next group (consumed ~1100 cycles from now)
        float em_n[4]; int tg_n[4];
#pragma unroll
        for (int u = 0; u < 4; ++u) {
            int tt = t + 4 + u; int ttc = tt < SEQ ? tt : SEQ - 1;
            em_n[u] = em[((size_t)ttc * BATCH + b) * NTAGS + j];
            tg_n[u] = tags[ttc * BATCH + b];
        }

        // off-path: exp of emissions for this group
        float eem[4];
#pragma unroll
        for (int u = 0; u < 4; ++u) eem[u] = __expf(em_c[u]);

        // off-path numerator lookups: LDS reads + bpermutes issued now,
        // consumed after the group's dots (DS pipe is in-order per wave)
        float tr0 = trans_sh[prev    * NTAGS + tg_c[0]];
        float tr1 = trans_sh[tg_c[0] * NTAGS + tg_c[1]];
        float tr2 = trans_sh[tg_c[1] * NTAGS + tg_c[2]];
        float tr3 = trans_sh[tg_c[2] * NTAGS + tg_c[3]];
        float ge0 = __shfl(em_c[0], tg_c[0]);
        float ge1 = __shfl(em_c[1], tg_c[1]);
        float ge2 = __shfl(em_c[2], tg_c[2]);
        float ge3 = __shfl(em_c[3], tg_c[3]);

        float rs = 1.f, rinv = 1.f;
        float s;

        // u = 0
        DOT_BODY(s); beta = s * eem[0];
        // u = 1
        DOT_BODY(s); beta = s * eem[1];
        rs = __shfl(beta, 0);              // stale scale; ready by u=3
        // u = 2
        DOT_BODY(s); beta = s * eem[2];
        rinv = 1.0f / rs;                  // off-path
        // u = 3: fold renorm into the emission factor
        DOT_BODY(s); beta = s * (eem[3] * rinv);
        M += __logf(rs);

        num += (tr0 + ge0) + (tr1 + ge1) + (tr2 + ge2) + (tr3 + ge3);
        prev = tg_c[3];

#pragma unroll
        for (int u = 0; u < 4; ++u) { em_c[u] = em_n[u]; tg_c[u] = tg_n[u]; }
        t += 4;
    }

    // tail: at most 3 steps, simple per-step renorm
    for (; t <= L - 1; ++t) {
        float emt = em[((size_t)t * BATCH + b) * NTAGS + j];
        int   cur = tags[t * BATCH + b];
        num += trans_sh[prev * NTAGS + cur] + __shfl(emt, cur);
        prev = cur;

        float s;
        DOT_BODY(s);
        beta = s * __expf(emt);
        float r = __shfl(beta, 0);
        beta *= (1.0f / r);
        M += __logf(r);
    }

    num += endT[prev];

    // denominator = M + log(sum_j beta_j * exp(end_j))
    float v = beta * eend;
#pragma unroll
    for (int off = 32; off > 0; off >>= 1)
        v += __shfl_xor(v, off);
    float denom = M + __logf(v);

    if (j == 0)
        atomicAdd(out, num - denom);
}

extern "C" void kernel_launch(void* const* d_in, const int* in_sizes, int n_in,
                              void* d_out, int out_size, void* d_ws, size_t ws_size,
                              hipStream_t stream)
{
    const float* em     = (const float*)d_in[0];
    const int*   tags   = (const int*)d_in[1];
    const int*   mask   = (const int*)d_in[2];
    const float* startT = (const float*)d_in[3];
    const float* endT   = (const float*)d_in[4];
    const float* trans  = (const float*)d_in[5];
    float*       out    = (float*)d_out;

    hipMemsetAsync(out, 0, sizeof(float) * out_size, stream);
    crf_kernel<<<BATCH, 64, 0, stream>>>(em, tags, mask, startT, endT, trans, out);
}